// Round 9
// baseline (687.124 us; speedup 1.0000x reference)
//
#include <hip/hip_runtime.h>
#include <hip/hip_bf16.h>

#define BATCH   64
#define LEN     288
#define DIM     256
#define PAST    12
#define NWIN    (LEN - PAST)        // 276
#define M_DIM   (BATCH * NWIN)      // 17664
#define K_DIM   (PAST * DIM)        // 3072
#define N_DIM   3072

#define BM 256
#define BN 256
#define BK 64
#define NTILE   (K_DIM / BK)        // 48
#define NITER   (NTILE / 2)         // 24

#define GRID_N   12
#define BULK_WG  768                 // 64 bm x 12 bn = exactly 3 rounds @256 CU
#define TAIL_M0  16384
#define TAIL_QN  24
#define TAIL_WG  240                 // 10 x 24 quarter tiles (128x128)

typedef __attribute__((ext_vector_type(8))) short bh8;
typedef __attribute__((ext_vector_type(4))) float f32x4;

__device__ __forceinline__ void llds16(const void* g, void* l) {
    __builtin_amdgcn_global_load_lds(
        (const __attribute__((address_space(1))) unsigned int*)g,
        (__attribute__((address_space(3))) unsigned int*)l,
        16, 0, 0);
}

__global__ void cvt_f32_bf16(const float* __restrict__ in,
                             __hip_bfloat16* __restrict__ out, int n8) {
    int i = blockIdx.x * blockDim.x + threadIdx.x;
    if (i >= n8) return;
    const float4* p = (const float4*)in;
    float4 a = p[2 * i], b = p[2 * i + 1];
    union { __hip_bfloat16 h[8]; int4 v; } u;
    u.h[0] = __float2bfloat16(a.x); u.h[1] = __float2bfloat16(a.y);
    u.h[2] = __float2bfloat16(a.z); u.h[3] = __float2bfloat16(a.w);
    u.h[4] = __float2bfloat16(b.x); u.h[5] = __float2bfloat16(b.y);
    u.h[6] = __float2bfloat16(b.z); u.h[7] = __float2bfloat16(b.w);
    ((int4*)out)[i] = u.v;
}

#define PH_MID  __builtin_amdgcn_s_barrier(); __builtin_amdgcn_s_setprio(1);
#define PH_END  __builtin_amdgcn_s_setprio(0); __builtin_amdgcn_s_barrier();
#define PH_END_VM(N) __builtin_amdgcn_s_setprio(0); \
                asm volatile("s_waitcnt vmcnt(" #N ")" ::: "memory"); \
                __builtin_amdgcn_s_barrier();

// ====================== BULK: 256x256, A direct-from-global ======================
// LDS holds ONLY B: buf0 @0, buf1 @32768 (64 KB total). A-fragments are loaded
// straight from global (each row's K64-slice = one 128B cacheline; 4x wn-reuse
// absorbed by L1/L2) with a one-phase register ping-pong (aP/aQ) lead.
// Per phase: 16 MFMA (4m x 4n x 1 k-half), 4 A-loads, 0-4 B ds_reads.
// Per-acc-cell accumulation order (kh0 then kh1 per K-tile) identical to R4.
#define BLDS(buf) (smem + (buf) * 32768)

#define RD_B4(buf, dst, KO) { \
    const char* _b = BLDS(buf) + bRowB; \
    _Pragma("unroll") for (int ni = 0; ni < 4; ++ni) \
        dst[ni] = *(const bh8*)(_b + ni * 2048 + (KO)); }
#define GA4(dst, mi0, ktv, half) { \
    _Pragma("unroll") for (int mi = 0; mi < 4; ++mi) \
        dst[mi] = *(const bh8*)((const char*)Ag + \
            (size_t)(unsigned)(aoffB[(mi0) + mi] + (ktv) * 128 + (half) * 64)); }
#define MFMA_K16(MB, AS, BS) \
    _Pragma("unroll") for (int mi = 0; mi < 4; ++mi) \
    _Pragma("unroll") for (int ni = 0; ni < 4; ++ni) \
        acc[(MB) + mi][ni] = __builtin_amdgcn_mfma_f32_16x16x32_bf16( \
            AS[mi], BS[ni], acc[(MB) + mi][ni], 0, 0, 0);
#define BSTG(buf, kt, u) \
    llds16(Wg + bSrc[u] + (kt) * 64, BLDS(buf) + (u) * 8192 + wOff);

__global__ __launch_bounds__(512, 2)
void gemm_bulk(const __hip_bfloat16* __restrict__ Ag,
               const __hip_bfloat16* __restrict__ Wg,
               const float* __restrict__ bias,
               float* __restrict__ C)
{
    extern __shared__ char smem[];

    const int tid = threadIdx.x;
    const int wgid = (blockIdx.x & 7) * (BULK_WG / 8) + (blockIdx.x >> 3);
    const int bm = wgid / GRID_N;
    const int bn = wgid - bm * GRID_N;
    const int tile_m = bm * BM;
    const int tile_n = bn * BN;

    // B staging (pre-swizzled global source, linear LDS dest) — unchanged, proven
    const int rd  = tid >> 3;
    const int chs = (((tid & 7) ^ (rd & 7)) * 8);
    int bSrc[4];
#pragma unroll
    for (int rb = 0; rb < 4; ++rb)
        bSrc[rb] = (tile_n + rb * 64 + rd) * K_DIM + chs;

    const int wave = tid >> 6, lane = tid & 63;
    const int wm = wave >> 2, wn = wave & 3;
    const int fr = lane & 15, kg = lane >> 4;
    const int sw    = (fr & 7) << 4;
    const int kOff0 = (kg * 16) ^ sw;
    const int kOff1 = kOff0 ^ 64;
    const int bRowB = (wn * 64 + fr) * 128;
    const int wOff  = wave * 1024;

    // A per-lane row byte-offsets: frag row m = tile_m + wm*128 + mi*16 + fr,
    // k-elems = kt*64 + half*32 + kg*8 .. +8  (window rows are contiguous)
    int aoffB[8];
#pragma unroll
    for (int mi = 0; mi < 8; ++mi) {
        int m  = tile_m + wm * 128 + mi * 16 + fr;
        int bq = m / NWIN;
        int wq = m - bq * NWIN;
        aoffB[mi] = ((bq * LEN + wq) * DIM + kg * 8) * 2;
    }

    bh8 aP[4], aQ[4], bK0[4], bK1[4];
    f32x4 acc[8][4] = {};

    // prologue: B of tile0 -> buf0, tile1 -> buf1; first A-set (mLo kh0, tile0)
    BSTG(0, 0, 0); BSTG(0, 0, 1); BSTG(0, 0, 2); BSTG(0, 0, 3);
    BSTG(1, 1, 0); BSTG(1, 1, 1); BSTG(1, 1, 2); BSTG(1, 1, 3);
    GA4(aP, 0, 0, 0);
    asm volatile("s_waitcnt vmcnt(8)" ::: "memory");   // tile0.B (oldest 4) landed
    __builtin_amdgcn_s_barrier();

#pragma unroll 1
    for (int it = 0; it < NITER; ++it) {
        const int kt0 = 2 * it, kt1 = 2 * it + 1;
        const int t2  = (it < NITER - 1) ? 2 * it + 2 : NTILE - 2;  // same-bytes rewrite
        const int t3  = (it < NITER - 1) ? 2 * it + 3 : NTILE - 1;
        const int tn0 = (it < NITER - 1) ? 2 * it + 2 : 0;          // A prefetch (unused last)

        // ph0: rd bK0(buf0); issue A mLo kh1 | MFMA mLo kh0
        RD_B4(0, bK0, kOff0);
        GA4(aQ, 0, kt0, 1);
        PH_MID; MFMA_K16(0, aP, bK0); PH_END;

        // ph1: rd bK1(buf0); issue A mHi kh0 | MFMA mLo kh1
        RD_B4(0, bK1, kOff1);
        GA4(aP, 4, kt0, 0);
        PH_MID; MFMA_K16(0, aQ, bK1); PH_END;

        // ph2: issue A mHi kh1; stage t2.B -> buf0 (freed after ph1) | MFMA mHi kh0
        GA4(aQ, 4, kt0, 1);
        BSTG(0, t2, 0); BSTG(0, t2, 1); BSTG(0, t2, 2); BSTG(0, t2, 3);
        PH_MID; MFMA_K16(4, aP, bK0); PH_END;

        // ph3: issue A mLo kh0 (tile1) | MFMA mHi kh1; force t2.B + older landed
        GA4(aP, 0, kt1, 0);
        PH_MID; MFMA_K16(4, aQ, bK1); PH_END_VM(4);

        // ph4-7: tile1 from buf1, stage t3.B -> buf1, prefetch next-iter A
        RD_B4(1, bK0, kOff0);
        GA4(aQ, 0, kt1, 1);
        PH_MID; MFMA_K16(0, aP, bK0); PH_END;

        RD_B4(1, bK1, kOff1);
        GA4(aP, 4, kt1, 0);
        PH_MID; MFMA_K16(0, aQ, bK1); PH_END;

        GA4(aQ, 4, kt1, 1);
        BSTG(1, t3, 0); BSTG(1, t3, 1); BSTG(1, t3, 2); BSTG(1, t3, 3);
        PH_MID; MFMA_K16(4, aP, bK0); PH_END;

        GA4(aP, 0, tn0, 0);
        PH_MID; MFMA_K16(4, aQ, bK1); PH_END_VM(4);
    }

    float bv[4];
    const float* bp = bias + tile_n + wn * 64 + fr;
#pragma unroll
    for (int ni = 0; ni < 4; ++ni) bv[ni] = bp[ni * 16];

    const int r0 = (lane >> 4) * 4;
#pragma unroll
    for (int mi = 0; mi < 8; ++mi) {
#pragma unroll
        for (int j = 0; j < 4; ++j) {
            long m = tile_m + wm * 128 + mi * 16 + r0 + j;
            float* crow = C + m * (long)N_DIM + tile_n + wn * 64 + fr;
#pragma unroll
            for (int ni = 0; ni < 4; ++ni)
                __builtin_nontemporal_store(acc[mi][ni][j] + bv[ni], &crow[ni * 16]);
        }
    }
}

// ============================ TAIL: 128x128, 16x16x32 (unchanged, proven) ============================
#define TLDS_A(buf) (smem + (buf) * 32768)
#define TLDS_B(buf) (smem + (buf) * 32768 + 16384)

#define T_RD(buf) { \
    const char* _bb = TLDS_B(buf) + bRowB; \
    _Pragma("unroll") for (int ni = 0; ni < 2; ++ni) { \
        fb0[ni][0] = *(const bh8*)(_bb + ni * 2048 + kOff0); \
        fb0[ni][1] = *(const bh8*)(_bb + ni * 2048 + kOff1); \
    } \
    const char* _a = TLDS_A(buf) + aRowB; \
    _Pragma("unroll") for (int mi = 0; mi < 4; ++mi) { \
        a0[mi][0] = *(const bh8*)(_a + mi * 2048 + kOff0); \
        a0[mi][1] = *(const bh8*)(_a + mi * 2048 + kOff1); \
    } }
#define T_MFMA(MB) \
    _Pragma("unroll") for (int mi = 0; mi < 2; ++mi) \
    _Pragma("unroll") for (int ni = 0; ni < 2; ++ni) { \
        acc[MB + mi][ni] = __builtin_amdgcn_mfma_f32_16x16x32_bf16( \
            a0[MB + mi][0], fb0[ni][0], acc[MB + mi][ni], 0, 0, 0); \
        acc[MB + mi][ni] = __builtin_amdgcn_mfma_f32_16x16x32_bf16( \
            a0[MB + mi][1], fb0[ni][1], acc[MB + mi][ni], 0, 0, 0); \
    }
#define T_STG_A(buf, kt, u) \
    llds16(Ag + aSrc[u] + (kt) * 64, TLDS_A(buf) + (u) * 8192 + wOff);
#define T_STG_B(buf, kt, u) \
    llds16(Wg + bSrc[u] + (kt) * 64, TLDS_B(buf) + (u) * 8192 + wOff);

__global__ __launch_bounds__(512, 2)
void gemm_tail(const __hip_bfloat16* __restrict__ Ag,
               const __hip_bfloat16* __restrict__ Wg,
               const float* __restrict__ bias,
               float* __restrict__ C)
{
    extern __shared__ char smem[];

    const int tid = threadIdx.x;
    const int wgid = (blockIdx.x & 7) * (TAIL_WG / 8) + (blockIdx.x >> 3);
    const int qm = wgid / TAIL_QN;
    const int qn = wgid - qm * TAIL_QN;
    const int tile_m = TAIL_M0 + qm * 128;
    const int tile_n = qn * 128;

    const int rd  = tid >> 3;
    const int chs = (((tid & 7) ^ (rd & 7)) * 8);
    int aSrc[2], bSrc[2];
#pragma unroll
    for (int rb = 0; rb < 2; ++rb) {
        int m  = tile_m + rb * 64 + rd;
        int bq = m / NWIN;
        int wq = m - bq * NWIN;
        aSrc[rb] = (bq * LEN + wq) * DIM + chs;
        bSrc[rb] = (tile_n + rb * 64 + rd) * K_DIM + chs;
    }

    const int wave = tid >> 6, lane = tid & 63;
    const int wm = wave >> 2, wn = wave & 3;             // per-wave 64x32
    const int fr = lane & 15, kg = lane >> 4;
    const int sw    = (fr & 7) << 4;
    const int kOff0 = (kg * 16) ^ sw;
    const int kOff1 = kOff0 ^ 64;
    const int aRowB = (wm * 64 + fr) * 128;
    const int bRowB = (wn * 32 + fr) * 128;
    const int wOff  = wave * 1024;

    bh8 a0[4][2], fb0[2][2];
    f32x4 acc[4][2] = {};

    T_STG_A(0, 0, 0); T_STG_A(0, 0, 1); T_STG_B(0, 0, 0); T_STG_B(0, 0, 1);
    T_STG_A(1, 1, 0); T_STG_A(1, 1, 1);
    asm volatile("s_waitcnt vmcnt(2)" ::: "memory");
    __builtin_amdgcn_s_barrier();

#pragma unroll 1
    for (int it = 0; it < NITER; ++it) {
        const int b = 2 * it + 1;
        int c = 2 * it + 2; if (c >= NTILE) c = NTILE - 2;
        int d = 2 * it + 3; if (d >= NTILE) d = NTILE - 1;

        T_RD(0);
        T_STG_B(1, b, 0); T_STG_B(1, b, 1);
        PH_MID; T_MFMA(0); PH_END;

        T_STG_A(0, c, 0); T_STG_A(0, c, 1);
        PH_MID; T_MFMA(2); PH_END_VM(2);

        T_RD(1);
        T_STG_B(0, c, 0); T_STG_B(0, c, 1);
        PH_MID; T_MFMA(0); PH_END;

        T_STG_A(1, d, 0); T_STG_A(1, d, 1);
        PH_MID; T_MFMA(2); PH_END_VM(2);
    }

    float bv[2];
    const float* bp = bias + tile_n + wn * 32 + fr;
#pragma unroll
    for (int ni = 0; ni < 2; ++ni) bv[ni] = bp[ni * 16];

    const int r0 = (lane >> 4) * 4;
#pragma unroll
    for (int mi = 0; mi < 4; ++mi) {
#pragma unroll
        for (int j = 0; j < 4; ++j) {
            long m = tile_m + wm * 64 + mi * 16 + r0 + j;
            float* crow = C + m * (long)N_DIM + tile_n + wn * 32 + fr;
#pragma unroll
            for (int ni = 0; ni < 2; ++ni)
                __builtin_nontemporal_store(acc[mi][ni][j] + bv[ni], &crow[ni * 16]);
        }
    }
}

extern "C" void kernel_launch(void* const* d_in, const int* in_sizes, int n_in,
                              void* d_out, int out_size, void* d_ws, size_t ws_size,
                              hipStream_t stream) {
    const float* inp  = (const float*)d_in[0];
    const float* Wf   = (const float*)d_in[1];
    const float* bias = (const float*)d_in[2];
    float* out = (float*)d_out;

    __hip_bfloat16* Abf = (__hip_bfloat16*)d_ws;
    __hip_bfloat16* Wbf = (__hip_bfloat16*)((char*)d_ws + (size_t)BATCH * LEN * DIM * 2);

    const int nA8 = BATCH * LEN * DIM / 8;
    const int nW8 = N_DIM * K_DIM / 8;
    cvt_f32_bf16<<<(nA8 + 255) / 256, 256, 0, stream>>>(inp, Abf, nA8);
    cvt_f32_bf16<<<(nW8 + 255) / 256, 256, 0, stream>>>(Wf, Wbf, nW8);

    hipFuncSetAttribute((const void*)gemm_bulk,
                        hipFuncAttributeMaxDynamicSharedMemorySize, 65536);
    hipFuncSetAttribute((const void*)gemm_tail,
                        hipFuncAttributeMaxDynamicSharedMemorySize, 65536);
    gemm_bulk<<<dim3(BULK_WG), 512, 65536, stream>>>(Abf, Wbf, bias, out);
    gemm_tail<<<dim3(TAIL_WG), 512, 65536, stream>>>(Abf, Wbf, bias, out);
}

// Round 11
// 329.440 us; speedup vs baseline: 2.0857x; 2.0857x over previous
//
#include <hip/hip_runtime.h>
#include <hip/hip_bf16.h>

#define BATCH   64
#define LEN     288
#define DIM     256
#define PAST    12
#define NWIN    (LEN - PAST)        // 276
#define M_DIM   (BATCH * NWIN)      // 17664
#define K_DIM   (PAST * DIM)        // 3072
#define N_DIM   3072

#define BM 256
#define BN 256
#define BK 64
#define NTILE   (K_DIM / BK)        // 48

#define GRID_N   12
#define BULK_WG  768                 // 64 bm x 12 bn = exactly 3 rounds @256 CU
#define TAIL_M0  16384
#define TAIL_QN  24
#define TAIL_WG  240                 // 10 x 24 quarter tiles (128x128)

typedef __attribute__((ext_vector_type(8))) short bh8;
typedef __attribute__((ext_vector_type(4))) float f32x4;

__device__ __forceinline__ void llds16(const void* g, void* l) {
    __builtin_amdgcn_global_load_lds(
        (const __attribute__((address_space(1))) unsigned int*)g,
        (__attribute__((address_space(3))) unsigned int*)l,
        16, 0, 0);
}

// merged f32->bf16 conversion for A and W in one launch
__global__ void cvt_both(const float* __restrict__ inA, const float* __restrict__ inW,
                         __hip_bfloat16* __restrict__ outA, __hip_bfloat16* __restrict__ outW,
                         int nA8, int nTot8) {
    int i = blockIdx.x * blockDim.x + threadIdx.x;
    if (i >= nTot8) return;
    const float* src;
    __hip_bfloat16* dst;
    int k;
    if (i < nA8) { src = inA; dst = outA; k = i; }
    else         { src = inW; dst = outW; k = i - nA8; }
    const float4* p = (const float4*)src;
    float4 a = p[2 * k], b = p[2 * k + 1];
    union { __hip_bfloat16 h[8]; int4 v; } u;
    u.h[0] = __float2bfloat16(a.x); u.h[1] = __float2bfloat16(a.y);
    u.h[2] = __float2bfloat16(a.z); u.h[3] = __float2bfloat16(a.w);
    u.h[4] = __float2bfloat16(b.x); u.h[5] = __float2bfloat16(b.y);
    u.h[6] = __float2bfloat16(b.z); u.h[7] = __float2bfloat16(b.w);
    ((int4*)dst)[k] = u.v;
}

// sched_barrier(0) pins are LOAD-BEARING for correctness: raw s_barrier is not
// a compiler memory fence (R10 raced without them; R4/R7 passed with them).
#define SB0 __builtin_amdgcn_sched_barrier(0)
#define PH_MID  SB0; __builtin_amdgcn_s_barrier(); SB0; __builtin_amdgcn_s_setprio(1);
#define PH_END  __builtin_amdgcn_s_setprio(0); SB0; __builtin_amdgcn_s_barrier(); SB0;
#define PH_END_VM(N) __builtin_amdgcn_s_setprio(0); SB0; \
                asm volatile("s_waitcnt vmcnt(" #N ")" ::: "memory"); \
                __builtin_amdgcn_s_barrier(); SB0;

// ========== BULK: 256x256, 4 phases per 2 K-tiles (2 phases/K-tile) ==========
// LDS 160KB: A double-buffered @0/32768 (64KB); B triple-buffered @65536+32768*r.
// Per K-tile t (rA=t%2, rB=t%3):
//   phase A: rd fb(B,rB) 8 + aLo(A,rA) 8; stage A(t+1)->Abuf[(t+1)%2];
//            barrier; 32 MFMA (mLo); barrier
//   phase B: rd aHi(A,rA) 8; stage B(t+2)->Bbuf[(t+2)%3];
//            barrier; 32 MFMA (mHi); vmcnt(4); barrier
// Race audit (with SB0 pins, schedule executes as written):
//  - WAR A: tile t phB reads Abuf[t%2], consumed pre-PH_END_VM barrier; write of
//    A(t+2) into Abuf[t%2] issues in t+1 phA, after that barrier. SAFE.
//  - WAR B: Bbuf[t%3] last read t phA (ds complete pre-phA-MFMA); rewritten as
//    B(t+3) in t+1 phB, >=3 barriers later. SAFE.
//  - RAW: vmcnt(4) at t phB end leaves only B(t+2) in flight => A(t+1), B(t+1)
//    landed before the barrier preceding their first read in t+1 phA. SAFE.
#define ALDS(r) (smem + (r) * 32768)
#define BLDS(r) (smem + 65536 + (r) * 32768)

#define RD_FB(r) { \
    const char* _b = BLDS(r) + bRowB; \
    _Pragma("unroll") for (int ni = 0; ni < 4; ++ni) { \
        fb[ni][0] = *(const bh8*)(_b + ni * 2048 + kOff0); \
        fb[ni][1] = *(const bh8*)(_b + ni * 2048 + kOff1); \
    } }
#define RD_A(r, MB) { \
    const char* _b = ALDS(r) + aRowB; \
    _Pragma("unroll") for (int mi = 0; mi < 4; ++mi) { \
        a0[mi][0] = *(const bh8*)(_b + ((MB) + mi) * 2048 + kOff0); \
        a0[mi][1] = *(const bh8*)(_b + ((MB) + mi) * 2048 + kOff1); \
    } }
#define MFMA_PH(MB) \
    _Pragma("unroll") for (int mi = 0; mi < 4; ++mi) \
    _Pragma("unroll") for (int ni = 0; ni < 4; ++ni) { \
        acc[(MB) + mi][ni] = __builtin_amdgcn_mfma_f32_16x16x32_bf16( \
            a0[mi][0], fb[ni][0], acc[(MB) + mi][ni], 0, 0, 0); \
        acc[(MB) + mi][ni] = __builtin_amdgcn_mfma_f32_16x16x32_bf16( \
            a0[mi][1], fb[ni][1], acc[(MB) + mi][ni], 0, 0, 0); \
    }
#define STG_A4(r, kt) { \
    llds16(Ag + aSrc[0] + (kt) * 64, ALDS(r) + 0 * 8192 + wOff); \
    llds16(Ag + aSrc[1] + (kt) * 64, ALDS(r) + 1 * 8192 + wOff); \
    llds16(Ag + aSrc[2] + (kt) * 64, ALDS(r) + 2 * 8192 + wOff); \
    llds16(Ag + aSrc[3] + (kt) * 64, ALDS(r) + 3 * 8192 + wOff); }
#define STG_B4(r, kt) { \
    llds16(Wg + bSrc[0] + (kt) * 64, BLDS(r) + 0 * 8192 + wOff); \
    llds16(Wg + bSrc[1] + (kt) * 64, BLDS(r) + 1 * 8192 + wOff); \
    llds16(Wg + bSrc[2] + (kt) * 64, BLDS(r) + 2 * 8192 + wOff); \
    llds16(Wg + bSrc[3] + (kt) * 64, BLDS(r) + 3 * 8192 + wOff); }

#define TILE(t, r2, r3, ra2, rn3) { \
    const int _tA = ((t) + 1 < NTILE) ? (t) + 1 : NTILE - 1; \
    const int _tB = ((t) + 2 < NTILE) ? (t) + 2 : NTILE - 1; \
    RD_FB(r3); RD_A(r2, 0); \
    STG_A4(ra2, _tA); \
    PH_MID; MFMA_PH(0); PH_END; \
    RD_A(r2, 4); \
    STG_B4(rn3, _tB); \
    PH_MID; MFMA_PH(4); PH_END_VM(4); \
}

__global__ __launch_bounds__(512, 2)
void gemm_bulk(const __hip_bfloat16* __restrict__ Ag,
               const __hip_bfloat16* __restrict__ Wg,
               const float* __restrict__ bias,
               float* __restrict__ C)
{
    extern __shared__ char smem[];

    const int tid = threadIdx.x;
    const int wgid = (blockIdx.x & 7) * (BULK_WG / 8) + (blockIdx.x >> 3);
    const int bm = wgid / GRID_N;
    const int bn = wgid - bm * GRID_N;
    const int tile_m = bm * BM;
    const int tile_n = bn * BN;

    const int rd  = tid >> 3;
    const int chs = (((tid & 7) ^ (rd & 7)) * 8);
    int aSrc[4], bSrc[4];
#pragma unroll
    for (int rb = 0; rb < 4; ++rb) {
        int m  = tile_m + rb * 64 + rd;
        int bq = m / NWIN;
        int wq = m - bq * NWIN;
        aSrc[rb] = (bq * LEN + wq) * DIM + chs;          // window rows contiguous
        bSrc[rb] = (tile_n + rb * 64 + rd) * K_DIM + chs;
    }

    const int wave = tid >> 6, lane = tid & 63;
    const int wm = wave >> 2, wn = wave & 3;
    const int fr = lane & 15, kg = lane >> 4;
    const int sw    = (fr & 7) << 4;
    const int kOff0 = (kg * 16) ^ sw;
    const int kOff1 = kOff0 ^ 64;
    const int aRowB = (wm * 128 + fr) * 128;
    const int bRowB = (wn * 64 + fr) * 128;
    const int wOff  = wave * 1024;

    bh8 a0[4][2], fb[4][2];
    f32x4 acc[8][4] = {};

    // prologue: t0.B->Bbuf0, t0.A->Abuf0, t1.B->Bbuf1 (t1.B issued last)
    STG_B4(0, 0);
    STG_A4(0, 0);
    STG_B4(1, 1);
    asm volatile("s_waitcnt vmcnt(4)" ::: "memory");     // t0 fully landed
    __builtin_amdgcn_s_barrier();
    SB0;

#pragma unroll 1
    for (int j = 0; j < NTILE / 6; ++j) {
        const int t = 6 * j;
        TILE(t + 0, 0, 0, 1, 2);
        TILE(t + 1, 1, 1, 0, 0);
        TILE(t + 2, 0, 2, 1, 1);
        TILE(t + 3, 1, 0, 0, 2);
        TILE(t + 4, 0, 1, 1, 0);
        TILE(t + 5, 1, 2, 0, 1);
    }

    float bv[4];
    const float* bp = bias + tile_n + wn * 64 + fr;
#pragma unroll
    for (int ni = 0; ni < 4; ++ni) bv[ni] = bp[ni * 16];

    const int r0 = (lane >> 4) * 4;
#pragma unroll
    for (int mi = 0; mi < 8; ++mi) {
#pragma unroll
        for (int j = 0; j < 4; ++j) {
            long m = tile_m + wm * 128 + mi * 16 + r0 + j;
            float* crow = C + m * (long)N_DIM + tile_n + wn * 64 + fr;
#pragma unroll
            for (int ni = 0; ni < 4; ++ni)
                __builtin_nontemporal_store(acc[mi][ni][j] + bv[ni], &crow[ni * 16]);
        }
    }
}

// ============================ TAIL: 128x128, 16x16x32 (R4/R7-proven) ============================
#define TLDS_A(buf) (smem + (buf) * 32768)
#define TLDS_B(buf) (smem + (buf) * 32768 + 16384)

#define T_RD(buf) { \
    const char* _bb = TLDS_B(buf) + bRowB; \
    _Pragma("unroll") for (int ni = 0; ni < 2; ++ni) { \
        fb0[ni][0] = *(const bh8*)(_bb + ni * 2048 + kOff0); \
        fb0[ni][1] = *(const bh8*)(_bb + ni * 2048 + kOff1); \
    } \
    const char* _a = TLDS_A(buf) + aRowB; \
    _Pragma("unroll") for (int mi = 0; mi < 4; ++mi) { \
        a0[mi][0] = *(const bh8*)(_a + mi * 2048 + kOff0); \
        a0[mi][1] = *(const bh8*)(_a + mi * 2048 + kOff1); \
    } }
#define T_MFMA(MB) \
    _Pragma("unroll") for (int mi = 0; mi < 2; ++mi) \
    _Pragma("unroll") for (int ni = 0; ni < 2; ++ni) { \
        acc[MB + mi][ni] = __builtin_amdgcn_mfma_f32_16x16x32_bf16( \
            a0[MB + mi][0], fb0[ni][0], acc[MB + mi][ni], 0, 0, 0); \
        acc[MB + mi][ni] = __builtin_amdgcn_mfma_f32_16x16x32_bf16( \
            a0[MB + mi][1], fb0[ni][1], acc[MB + mi][ni], 0, 0, 0); \
    }
#define T_STG_A(buf, kt, u) \
    llds16(Ag + aSrc[u] + (kt) * 64, TLDS_A(buf) + (u) * 8192 + wOff);
#define T_STG_B(buf, kt, u) \
    llds16(Wg + bSrc[u] + (kt) * 64, TLDS_B(buf) + (u) * 8192 + wOff);

__global__ __launch_bounds__(512, 2)
void gemm_tail(const __hip_bfloat16* __restrict__ Ag,
               const __hip_bfloat16* __restrict__ Wg,
               const float* __restrict__ bias,
               float* __restrict__ C)
{
    extern __shared__ char smem[];

    const int tid = threadIdx.x;
    const int wgid = (blockIdx.x & 7) * (TAIL_WG / 8) + (blockIdx.x >> 3);
    const int qm = wgid / TAIL_QN;
    const int qn = wgid - qm * TAIL_QN;
    const int tile_m = TAIL_M0 + qm * 128;
    const int tile_n = qn * 128;

    const int rd  = tid >> 3;
    const int chs = (((tid & 7) ^ (rd & 7)) * 8);
    int aSrc[2], bSrc[2];
#pragma unroll
    for (int rb = 0; rb < 2; ++rb) {
        int m  = tile_m + rb * 64 + rd;
        int bq = m / NWIN;
        int wq = m - bq * NWIN;
        aSrc[rb] = (bq * LEN + wq) * DIM + chs;
        bSrc[rb] = (tile_n + rb * 64 + rd) * K_DIM + chs;
    }

    const int wave = tid >> 6, lane = tid & 63;
    const int wm = wave >> 2, wn = wave & 3;             // per-wave 64x32
    const int fr = lane & 15, kg = lane >> 4;
    const int sw    = (fr & 7) << 4;
    const int kOff0 = (kg * 16) ^ sw;
    const int kOff1 = kOff0 ^ 64;
    const int aRowB = (wm * 64 + fr) * 128;
    const int bRowB = (wn * 32 + fr) * 128;
    const int wOff  = wave * 1024;

    bh8 a0[4][2], fb0[2][2];
    f32x4 acc[4][2] = {};

    T_STG_A(0, 0, 0); T_STG_A(0, 0, 1); T_STG_B(0, 0, 0); T_STG_B(0, 0, 1);
    T_STG_A(1, 1, 0); T_STG_A(1, 1, 1);
    asm volatile("s_waitcnt vmcnt(2)" ::: "memory");
    __builtin_amdgcn_s_barrier();
    SB0;

#pragma unroll 1
    for (int it = 0; it < NTILE / 2; ++it) {
        const int b = 2 * it + 1;
        int c = 2 * it + 2; if (c >= NTILE) c = NTILE - 2;
        int d = 2 * it + 3; if (d >= NTILE) d = NTILE - 1;

        T_RD(0);
        T_STG_B(1, b, 0); T_STG_B(1, b, 1);
        PH_MID; T_MFMA(0); PH_END;

        T_STG_A(0, c, 0); T_STG_A(0, c, 1);
        PH_MID; T_MFMA(2); PH_END_VM(2);

        T_RD(1);
        T_STG_B(0, c, 0); T_STG_B(0, c, 1);
        PH_MID; T_MFMA(0); PH_END;

        T_STG_A(1, d, 0); T_STG_A(1, d, 1);
        PH_MID; T_MFMA(2); PH_END_VM(2);
    }

    float bv[2];
    const float* bp = bias + tile_n + wn * 32 + fr;
#pragma unroll
    for (int ni = 0; ni < 2; ++ni) bv[ni] = bp[ni * 16];

    const int r0 = (lane >> 4) * 4;
#pragma unroll
    for (int mi = 0; mi < 4; ++mi) {
#pragma unroll
        for (int j = 0; j < 4; ++j) {
            long m = tile_m + wm * 64 + mi * 16 + r0 + j;
            float* crow = C + m * (long)N_DIM + tile_n + wn * 32 + fr;
#pragma unroll
            for (int ni = 0; ni < 2; ++ni)
                __builtin_nontemporal_store(acc[mi][ni][j] + bv[ni], &crow[ni * 16]);
        }
    }
}

extern "C" void kernel_launch(void* const* d_in, const int* in_sizes, int n_in,
                              void* d_out, int out_size, void* d_ws, size_t ws_size,
                              hipStream_t stream) {
    const float* inp  = (const float*)d_in[0];
    const float* Wf   = (const float*)d_in[1];
    const float* bias = (const float*)d_in[2];
    float* out = (float*)d_out;

    __hip_bfloat16* Abf = (__hip_bfloat16*)d_ws;
    __hip_bfloat16* Wbf = (__hip_bfloat16*)((char*)d_ws + (size_t)BATCH * LEN * DIM * 2);

    const int nA8 = BATCH * LEN * DIM / 8;   // 589824
    const int nW8 = N_DIM * K_DIM / 8;       // 1179648
    const int nT8 = nA8 + nW8;
    cvt_both<<<(nT8 + 255) / 256, 256, 0, stream>>>(inp, Wf, Abf, Wbf, nA8, nT8);

    hipFuncSetAttribute((const void*)gemm_bulk,
                        hipFuncAttributeMaxDynamicSharedMemorySize, 163840);
    hipFuncSetAttribute((const void*)gemm_tail,
                        hipFuncAttributeMaxDynamicSharedMemorySize, 65536);
    gemm_bulk<<<dim3(BULK_WG), 512, 163840, stream>>>(Abf, Wbf, bias, out);
    gemm_tail<<<dim3(TAIL_WG), 512, 65536, stream>>>(Abf, Wbf, bias, out);
}

// Round 12
// 299.026 us; speedup vs baseline: 2.2979x; 1.1017x over previous
//
#include <hip/hip_runtime.h>
#include <hip/hip_bf16.h>

#define BATCH   64
#define LEN     288
#define DIM     256
#define PAST    12
#define NWIN    (LEN - PAST)        // 276
#define M_DIM   (BATCH * NWIN)      // 17664
#define K_DIM   (PAST * DIM)        // 3072
#define N_DIM   3072

#define BM 256
#define BN 256
#define BK 64
#define NTILE   (K_DIM / BK)        // 48
#define NITER   (NTILE / 2)         // 24

#define GRID_N   12
#define BULK_WG  768                 // 64 bm x 12 bn = exactly 3 rounds @256 CU
#define TAIL_M0  16384
#define TAIL_QN  24
#define TAIL_WG  240                 // 10 x 24 quarter tiles (128x128)

typedef __attribute__((ext_vector_type(8))) short bh8;
typedef __attribute__((ext_vector_type(4))) float f32x4;

__device__ __forceinline__ void llds16(const void* g, void* l) {
    __builtin_amdgcn_global_load_lds(
        (const __attribute__((address_space(1))) unsigned int*)g,
        (__attribute__((address_space(3))) unsigned int*)l,
        16, 0, 0);
}

__global__ void cvt_both(const float* __restrict__ inA, const float* __restrict__ inW,
                         __hip_bfloat16* __restrict__ outA, __hip_bfloat16* __restrict__ outW,
                         int nA8, int nTot8) {
    int i = blockIdx.x * blockDim.x + threadIdx.x;
    if (i >= nTot8) return;
    const float* src;
    __hip_bfloat16* dst;
    int k;
    if (i < nA8) { src = inA; dst = outA; k = i; }
    else         { src = inW; dst = outW; k = i - nA8; }
    const float4* p = (const float4*)src;
    float4 a = p[2 * k], b = p[2 * k + 1];
    union { __hip_bfloat16 h[8]; int4 v; } u;
    u.h[0] = __float2bfloat16(a.x); u.h[1] = __float2bfloat16(a.y);
    u.h[2] = __float2bfloat16(a.z); u.h[3] = __float2bfloat16(a.w);
    u.h[4] = __float2bfloat16(b.x); u.h[5] = __float2bfloat16(b.y);
    u.h[6] = __float2bfloat16(b.z); u.h[7] = __float2bfloat16(b.w);
    ((int4*)dst)[k] = u.v;
}

// ONE barrier per phase (at the end). The old mid-phase barrier protected
// nothing: reads precede it and rely on the PREVIOUS phase-end barrier; the
// read->MFMA order is a register data-dep; WAR safety counts phase-END
// barriers only (a lagging wave's reads complete before it reaches the end
// barrier, forced by its MFMAs' lgkm waits). Removing it enables wave-skew:
// one wave's MFMA overlaps another wave's LDS reads.
// SB0 around each remaining barrier is LOAD-BEARING (R10: raw s_barrier is
// not a compiler memory fence; memory ops must not cross it).
#define SB0 __builtin_amdgcn_sched_barrier(0)
#define PH_MID  __builtin_amdgcn_s_setprio(1);
#define PH_END  __builtin_amdgcn_s_setprio(0); SB0; __builtin_amdgcn_s_barrier(); SB0;
#define PH_END_VM(N) __builtin_amdgcn_s_setprio(0); SB0; \
                asm volatile("s_waitcnt vmcnt(" #N ")" ::: "memory"); \
                __builtin_amdgcn_s_barrier(); SB0;

// ============================ BULK: 256x256, 16x16x32 ============================
#define LDS_A(buf) (smem + (buf) * 65536)
#define LDS_B(buf) (smem + (buf) * 65536 + 32768)

#define RD_A4(buf, MB) { \
    const char* _b = LDS_A(buf) + aRowB; \
    _Pragma("unroll") for (int mi = 0; mi < 4; ++mi) { \
        a0[mi][0] = *(const bh8*)(_b + (MB + mi) * 2048 + kOff0); \
        a0[mi][1] = *(const bh8*)(_b + (MB + mi) * 2048 + kOff1); \
    } }
#define RD_B2(buf, dst, NB) { \
    const char* _b = LDS_B(buf) + bRowB; \
    _Pragma("unroll") for (int ni = 0; ni < 2; ++ni) { \
        dst[ni][0] = *(const bh8*)(_b + (NB + ni) * 2048 + kOff0); \
        dst[ni][1] = *(const bh8*)(_b + (NB + ni) * 2048 + kOff1); \
    } }
#define MFMA_Q(MB, NB, BB) \
    _Pragma("unroll") for (int mi = 0; mi < 4; ++mi) \
    _Pragma("unroll") for (int ni = 0; ni < 2; ++ni) { \
        acc[MB + mi][NB + ni] = __builtin_amdgcn_mfma_f32_16x16x32_bf16( \
            a0[mi][0], BB[ni][0], acc[MB + mi][NB + ni], 0, 0, 0); \
        acc[MB + mi][NB + ni] = __builtin_amdgcn_mfma_f32_16x16x32_bf16( \
            a0[mi][1], BB[ni][1], acc[MB + mi][NB + ni], 0, 0, 0); \
    }
#define STG_A1(buf, kt, q) \
    llds16(Ag + aSrc[q] + (kt) * 64, LDS_A(buf) + (q) * 8192 + wOff);
#define STG_B1(buf, kt, u) \
    llds16(Wg + bSrc[u] + (kt) * 64, LDS_B(buf) + (u) * 8192 + wOff);

__global__ __launch_bounds__(512, 2)
void gemm_bulk(const __hip_bfloat16* __restrict__ Ag,
               const __hip_bfloat16* __restrict__ Wg,
               const float* __restrict__ bias,
               float* __restrict__ C)
{
    extern __shared__ char smem[];

    const int tid = threadIdx.x;
    const int wgid = (blockIdx.x & 7) * (BULK_WG / 8) + (blockIdx.x >> 3);
    const int bm = wgid / GRID_N;
    const int bn = wgid - bm * GRID_N;
    const int tile_m = bm * BM;
    const int tile_n = bn * BN;

    const int rd  = tid >> 3;
    const int chs = (((tid & 7) ^ (rd & 7)) * 8);
    int aSrc[4], bSrc[4];
#pragma unroll
    for (int rb = 0; rb < 4; ++rb) {
        int m  = tile_m + rb * 64 + rd;
        int bq = m / NWIN;
        int wq = m - bq * NWIN;
        aSrc[rb] = (bq * LEN + wq) * DIM + chs;
        bSrc[rb] = (tile_n + rb * 64 + rd) * K_DIM + chs;
    }

    const int wave = tid >> 6, lane = tid & 63;
    const int wm = wave >> 2, wn = wave & 3;
    const int fr = lane & 15, kg = lane >> 4;
    const int sw    = (fr & 7) << 4;
    const int kOff0 = (kg * 16) ^ sw;
    const int kOff1 = kOff0 ^ 64;
    const int aRowB = (wm * 128 + fr) * 128;
    const int bRowB = (wn * 64 + fr) * 128;
    const int wOff  = wave * 1024;

    bh8 a0[4][2], fb0[2][2], fb1[2][2];
    f32x4 acc[8][4] = {};

    STG_A1(0, 0, 0); STG_A1(0, 0, 1); STG_A1(0, 0, 2); STG_A1(0, 0, 3);
    STG_B1(0, 0, 0); STG_B1(0, 0, 1); STG_B1(0, 0, 2); STG_B1(0, 0, 3);
    STG_A1(1, 1, 0); STG_A1(1, 1, 2);
    STG_B1(1, 1, 0); STG_B1(1, 1, 1);
    STG_A1(1, 1, 1); STG_A1(1, 1, 3);
    asm volatile("s_waitcnt vmcnt(6)" ::: "memory");
    __builtin_amdgcn_s_barrier();
    SB0;

#pragma unroll 1
    for (int it = 0; it < NITER; ++it) {
        const int b = 2 * it + 1;
        int c = 2 * it + 2; if (c >= NTILE) c = NTILE - 2;
        int d = 2 * it + 3; if (d >= NTILE) d = NTILE - 1;

        // ph0: rd B n01 + A mLo (buf0); stage b.Bu2,Bu3 -> buf1
        RD_B2(0, fb0, 0); RD_A4(0, 0);
        STG_B1(1, b, 2); STG_B1(1, b, 3);
        PH_MID; MFMA_Q(0, 0, fb0); PH_END;

        RD_B2(0, fb1, 2);
        STG_A1(0, c, 0); STG_A1(0, c, 2);
        PH_MID; MFMA_Q(0, 2, fb1); PH_END;

        RD_A4(0, 4);
        STG_B1(0, c, 0); STG_B1(0, c, 1);
        PH_MID; MFMA_Q(4, 2, fb1); PH_END;

        STG_A1(0, c, 1); STG_A1(0, c, 3);
        PH_MID; MFMA_Q(4, 0, fb0); PH_END_VM(6);

        // ph4-7: buf1 (tile b), prefetch d
        RD_B2(1, fb0, 0); RD_A4(1, 0);
        STG_B1(0, c, 2); STG_B1(0, c, 3);
        PH_MID; MFMA_Q(0, 0, fb0); PH_END;

        RD_B2(1, fb1, 2);
        STG_A1(1, d, 0); STG_A1(1, d, 2);
        PH_MID; MFMA_Q(0, 2, fb1); PH_END;

        RD_A4(1, 4);
        STG_B1(1, d, 0); STG_B1(1, d, 1);
        PH_MID; MFMA_Q(4, 2, fb1); PH_END;

        STG_A1(1, d, 1); STG_A1(1, d, 3);
        PH_MID; MFMA_Q(4, 0, fb0); PH_END_VM(6);
    }

    float bv[4];
    const float* bp = bias + tile_n + wn * 64 + fr;
#pragma unroll
    for (int ni = 0; ni < 4; ++ni) bv[ni] = bp[ni * 16];

    const int r0 = (lane >> 4) * 4;
#pragma unroll
    for (int mi = 0; mi < 8; ++mi) {
#pragma unroll
        for (int j = 0; j < 4; ++j) {
            long m = tile_m + wm * 128 + mi * 16 + r0 + j;
            float* crow = C + m * (long)N_DIM + tile_n + wn * 64 + fr;
#pragma unroll
            for (int ni = 0; ni < 4; ++ni)
                __builtin_nontemporal_store(acc[mi][ni][j] + bv[ni], &crow[ni * 16]);
        }
    }
}

// ============================ TAIL: 128x128, 16x16x32 ============================
#define TLDS_A(buf) (smem + (buf) * 32768)
#define TLDS_B(buf) (smem + (buf) * 32768 + 16384)

#define T_RD(buf) { \
    const char* _bb = TLDS_B(buf) + bRowB; \
    _Pragma("unroll") for (int ni = 0; ni < 2; ++ni) { \
        fb0[ni][0] = *(const bh8*)(_bb + ni * 2048 + kOff0); \
        fb0[ni][1] = *(const bh8*)(_bb + ni * 2048 + kOff1); \
    } \
    const char* _a = TLDS_A(buf) + aRowB; \
    _Pragma("unroll") for (int mi = 0; mi < 4; ++mi) { \
        a0[mi][0] = *(const bh8*)(_a + mi * 2048 + kOff0); \
        a0[mi][1] = *(const bh8*)(_a + mi * 2048 + kOff1); \
    } }
#define T_MFMA(MB) \
    _Pragma("unroll") for (int mi = 0; mi < 2; ++mi) \
    _Pragma("unroll") for (int ni = 0; ni < 2; ++ni) { \
        acc[MB + mi][ni] = __builtin_amdgcn_mfma_f32_16x16x32_bf16( \
            a0[MB + mi][0], fb0[ni][0], acc[MB + mi][ni], 0, 0, 0); \
        acc[MB + mi][ni] = __builtin_amdgcn_mfma_f32_16x16x32_bf16( \
            a0[MB + mi][1], fb0[ni][1], acc[MB + mi][ni], 0, 0, 0); \
    }
#define T_STG_A(buf, kt, u) \
    llds16(Ag + aSrc[u] + (kt) * 64, TLDS_A(buf) + (u) * 8192 + wOff);
#define T_STG_B(buf, kt, u) \
    llds16(Wg + bSrc[u] + (kt) * 64, TLDS_B(buf) + (u) * 8192 + wOff);

__global__ __launch_bounds__(512, 2)
void gemm_tail(const __hip_bfloat16* __restrict__ Ag,
               const __hip_bfloat16* __restrict__ Wg,
               const float* __restrict__ bias,
               float* __restrict__ C)
{
    extern __shared__ char smem[];

    const int tid = threadIdx.x;
    const int wgid = (blockIdx.x & 7) * (TAIL_WG / 8) + (blockIdx.x >> 3);
    const int qm = wgid / TAIL_QN;
    const int qn = wgid - qm * TAIL_QN;
    const int tile_m = TAIL_M0 + qm * 128;
    const int tile_n = qn * 128;

    const int rd  = tid >> 3;
    const int chs = (((tid & 7) ^ (rd & 7)) * 8);
    int aSrc[2], bSrc[2];
#pragma unroll
    for (int rb = 0; rb < 2; ++rb) {
        int m  = tile_m + rb * 64 + rd;
        int bq = m / NWIN;
        int wq = m - bq * NWIN;
        aSrc[rb] = (bq * LEN + wq) * DIM + chs;
        bSrc[rb] = (tile_n + rb * 64 + rd) * K_DIM + chs;
    }

    const int wave = tid >> 6, lane = tid & 63;
    const int wm = wave >> 2, wn = wave & 3;             // per-wave 64x32
    const int fr = lane & 15, kg = lane >> 4;
    const int sw    = (fr & 7) << 4;
    const int kOff0 = (kg * 16) ^ sw;
    const int kOff1 = kOff0 ^ 64;
    const int aRowB = (wm * 64 + fr) * 128;
    const int bRowB = (wn * 32 + fr) * 128;
    const int wOff  = wave * 1024;

    bh8 a0[4][2], fb0[2][2];
    f32x4 acc[4][2] = {};

    T_STG_A(0, 0, 0); T_STG_A(0, 0, 1); T_STG_B(0, 0, 0); T_STG_B(0, 0, 1);
    T_STG_A(1, 1, 0); T_STG_A(1, 1, 1);
    asm volatile("s_waitcnt vmcnt(2)" ::: "memory");
    __builtin_amdgcn_s_barrier();
    SB0;

#pragma unroll 1
    for (int it = 0; it < NITER; ++it) {
        const int b = 2 * it + 1;
        int c = 2 * it + 2; if (c >= NTILE) c = NTILE - 2;
        int d = 2 * it + 3; if (d >= NTILE) d = NTILE - 1;

        T_RD(0);
        T_STG_B(1, b, 0); T_STG_B(1, b, 1);
        PH_MID; T_MFMA(0); PH_END;

        T_STG_A(0, c, 0); T_STG_A(0, c, 1);
        PH_MID; T_MFMA(2); PH_END_VM(2);

        T_RD(1);
        T_STG_B(0, c, 0); T_STG_B(0, c, 1);
        PH_MID; T_MFMA(0); PH_END;

        T_STG_A(1, d, 0); T_STG_A(1, d, 1);
        PH_MID; T_MFMA(2); PH_END_VM(2);
    }

    float bv[2];
    const float* bp = bias + tile_n + wn * 32 + fr;
#pragma unroll
    for (int ni = 0; ni < 2; ++ni) bv[ni] = bp[ni * 16];

    const int r0 = (lane >> 4) * 4;
#pragma unroll
    for (int mi = 0; mi < 4; ++mi) {
#pragma unroll
        for (int j = 0; j < 4; ++j) {
            long m = tile_m + wm * 64 + mi * 16 + r0 + j;
            float* crow = C + m * (long)N_DIM + tile_n + wn * 32 + fr;
#pragma unroll
            for (int ni = 0; ni < 2; ++ni)
                __builtin_nontemporal_store(acc[mi][ni][j] + bv[ni], &crow[ni * 16]);
        }
    }
}

extern "C" void kernel_launch(void* const* d_in, const int* in_sizes, int n_in,
                              void* d_out, int out_size, void* d_ws, size_t ws_size,
                              hipStream_t stream) {
    const float* inp  = (const float*)d_in[0];
    const float* Wf   = (const float*)d_in[1];
    const float* bias = (const float*)d_in[2];
    float* out = (float*)d_out;

    __hip_bfloat16* Abf = (__hip_bfloat16*)d_ws;
    __hip_bfloat16* Wbf = (__hip_bfloat16*)((char*)d_ws + (size_t)BATCH * LEN * DIM * 2);

    const int nA8 = BATCH * LEN * DIM / 8;   // 589824
    const int nW8 = N_DIM * K_DIM / 8;       // 1179648
    const int nT8 = nA8 + nW8;
    cvt_both<<<(nT8 + 255) / 256, 256, 0, stream>>>(inp, Wf, Abf, Wbf, nA8, nT8);

    hipFuncSetAttribute((const void*)gemm_bulk,
                        hipFuncAttributeMaxDynamicSharedMemorySize, 131072);
    hipFuncSetAttribute((const void*)gemm_tail,
                        hipFuncAttributeMaxDynamicSharedMemorySize, 65536);
    gemm_bulk<<<dim3(BULK_WG), 512, 131072, stream>>>(Abf, Wbf, bias, out);
    gemm_tail<<<dim3(TAIL_WG), 512, 65536, stream>>>(Abf, Wbf, bias, out);
}